// Round 12
// baseline (147.513 us; speedup 1.0000x reference)
//
#include <hip/hip_runtime.h>

#define T_SEQ 50
#define BATCH 8192
#define INPUT 33
#define HID   256
#define BTILE 32
#define NTH   512

typedef __attribute__((ext_vector_type(8))) short short8;
typedef __attribute__((ext_vector_type(4))) float float4v;
typedef __attribute__((ext_vector_type(2))) int   int2v;

// LDS (shorts): h dbuf (stride 264) + ALL 50 x tiles (stride 40, b128-aligned).
#define H_STRIDE 264
#define HBUF (BTILE * H_STRIDE)            // 8448
#define H0 0
#define H1 HBUF
#define XOFF (2 * HBUF)                    // 16896
#define X_ROW 40                           // 80 B rows: 16B-aligned; cols 0..31 bf16 x,
#define X_T (BTILE * X_ROW)                // cols 36..37 f32 x[.,32], rest 0
#define LDS_SHORTS (XOFF + T_SEQ * X_T)    // 80896 shorts
#define LDS_BYTES  (LDS_SHORTS * 2)        // 161792 <= 163840

__device__ __forceinline__ short f2bf(float v) {   // RNE f32 -> bf16 (init only)
  unsigned u = __builtin_bit_cast(unsigned, v);
  u = (u + 0x7FFFu + ((u >> 16) & 1u)) >> 16;
  return (short)u;
}

#define MFMA(a, b, c) __builtin_amdgcn_mfma_f32_16x16x32_bf16(a, b, c, 0, 0, 0)

// One step, minimal-VALU form (~45 VALU/thread):
//   acc = fma(w32, x32, bc)  [16 fma]  ->  36 MFMA (0.5 folded in weights)
//   -> 16 v_max (relu) -> 4 dwordx4 stores -> 8 cvt_pk + 4 ds_write_b64 restage
// NO global loads in loop (x pre-staged) -> no vmcnt waits; stores self-pace
// against HBM via the outstanding-op cap. One lgkm-only barrier per step.
#define CSTEP(HR, HW, T)                                                      \
  {                                                                           \
    const short* hb  = lds + (HR);                                            \
    const short* xst = lds + XOFF + (T) * X_T;                                \
    const float x32a = *(const float*)(xst + colA * X_ROW + 36);              \
    const float x32b = *(const float*)(xst + (16 + colA) * X_ROW + 36);       \
    float4v acc[2][2];                                                        \
    _Pragma("unroll") for (int jt = 0; jt < 2; ++jt)                          \
      _Pragma("unroll") for (int i = 0; i < 4; ++i) {                         \
        acc[jt][0][i] = fmaf(w32v[jt][i], x32a, bcv[jt][i]);                  \
        acc[jt][1][i] = fmaf(w32v[jt][i], x32b, bcv[jt][i]);                  \
      }                                                                       \
    _Pragma("unroll") for (int ks = 0; ks < 8; ++ks) {                        \
      const int k = ks * 32 + kq * 8;                                         \
      short8 b0 = *(const short8*)(hb + colA * H_STRIDE + k);                 \
      short8 b1 = *(const short8*)(hb + (16 + colA) * H_STRIDE + k);          \
      acc[0][0] = MFMA(wf[0][ks], b0, acc[0][0]);                             \
      acc[0][1] = MFMA(wf[0][ks], b1, acc[0][1]);                             \
      acc[1][0] = MFMA(wf[1][ks], b0, acc[1][0]);                             \
      acc[1][1] = MFMA(wf[1][ks], b1, acc[1][1]);                             \
    }                                                                         \
    {                                                                         \
      short8 xb0 = *(const short8*)(xst + colA * X_ROW + kq * 8);             \
      short8 xb1 = *(const short8*)(xst + (16 + colA) * X_ROW + kq * 8);      \
      acc[0][0] = MFMA(win[0], xb0, acc[0][0]);                               \
      acc[0][1] = MFMA(win[0], xb1, acc[0][1]);                               \
      acc[1][0] = MFMA(win[1], xb0, acc[1][0]);                               \
      acc[1][1] = MFMA(win[1], xb1, acc[1][1]);                               \
    }                                                                         \
    _Pragma("unroll") for (int jt = 0; jt < 2; ++jt)                          \
      _Pragma("unroll") for (int bt = 0; bt < 2; ++bt) {                      \
        float4v hv;                                                           \
        _Pragma("unroll") for (int i = 0; i < 4; ++i)                         \
          hv[i] = fmaxf(acc[jt][bt][i], 0.0f);                                \
        *(float4v*)((bt ? o1 : o0) + jt * 16) = hv;                           \
        int d0, d1;                                                           \
        asm("v_cvt_pk_bf16_f32 %0, %1, %2" : "=v"(d0) : "v"(hv[0]), "v"(hv[1])); \
        asm("v_cvt_pk_bf16_f32 %0, %1, %2" : "=v"(d1) : "v"(hv[2]), "v"(hv[3])); \
        int2v dd; dd[0] = d0; dd[1] = d1;                                     \
        *(int2v*)(lds + (HW) + (bt * 16 + colA) * H_STRIDE + c0 + jt * 16 +   \
                  kq * 4) = dd;                                               \
      }                                                                       \
    __builtin_amdgcn_sched_barrier(0);                                        \
    asm volatile("s_waitcnt lgkmcnt(0)" ::: "memory");                        \
    __builtin_amdgcn_s_barrier();                                             \
    __builtin_amdgcn_sched_barrier(0);                                        \
    o0 += outstep; o1 += outstep;                                             \
  }

__global__ __launch_bounds__(NTH, 2)
void ctrnn_kernel(const float* __restrict__ x, const int* __restrict__ sub_id,
                  const float* __restrict__ gates, const float* __restrict__ W_in,
                  const float* __restrict__ b_in, const float* __restrict__ W_h,
                  const float* __restrict__ b_h, float* __restrict__ out)
{
  extern __shared__ short lds[];
  const int tid  = threadIdx.x;
  const int lane = tid & 63;
  const int wave = tid >> 6;
  const int colA = lane & 15;   // batch row within tile / B-frag col / C col
  const int kq   = lane >> 4;   // k-chunk; C rows j = kq*4+i
  const int c0   = wave * 32;   // wave's hidden-j base (8 waves x 32 j)
  const int brow0 = blockIdx.x * BTILE;

  const int sid = sub_id[0];
  const float* grow = gates + sid * HID;

  // ---- zero ALL LDS (h0 = 0; x pad cols stay 0) ----
  {
    int* ldsi = (int*)lds;
    for (int i = tid; i < LDS_SHORTS / 2; i += NTH) ldsi[i] = 0;
  }

  // ---- t-invariant operands, all pre-scaled by ALPHA=0.5 ----
  // wf = 0.5*(I + diag(g)*W_h) fragments (A-operand, j rows = c0+jt*16+colA)
  // win = 0.5*W_in[:,0:32); w32v/bcv indexed by C-row j = c0+jt*16+kq*4+i
  short8  wf[2][8];
  short8  win[2];
  float4v w32v[2], bcv[2];
  #pragma unroll
  for (int jt = 0; jt < 2; ++jt) {
    const int col = c0 + jt * 16 + colA;
    const float g = grow[col];
    #pragma unroll
    for (int ks = 0; ks < 8; ++ks) {
      const int kbase = ks * 32 + kq * 8;
      const float* wp = W_h + col * HID + kbase;
      float4v w0 = *(const float4v*)wp;
      float4v w1 = *(const float4v*)(wp + 4);
      short8 f;
      #pragma unroll
      for (int j = 0; j < 8; ++j) {
        const float w = (j < 4) ? w0[j] : w1[j - 4];
        const float idt = (kbase + j == col) ? 1.0f : 0.0f;
        f[j] = f2bf(0.5f * (idt + g * w));
      }
      wf[jt][ks] = f;
    }
    {
      short8 f;
      #pragma unroll
      for (int j = 0; j < 8; ++j)
        f[j] = f2bf(0.5f * W_in[col * INPUT + kq * 8 + j]);   // k < 32
      win[jt] = f;
    }
    #pragma unroll
    for (int i = 0; i < 4; ++i) {
      const int jr = c0 + jt * 16 + kq * 4 + i;
      w32v[jt][i] = 0.5f * W_in[jr * INPUT + 32];
      bcv[jt][i]  = 0.5f * (b_in[jr] + grow[jr] * b_h[jr]);
    }
  }

  __syncthreads();   // zero-fill complete before x staging

  // ---- stage ALL 50 x tiles: bf16 cols 0..31, f32 x[.,32] at col 36 ----
  {
    const int xstep = BATCH * INPUT;
    for (int e = tid; e < T_SEQ * BTILE * INPUT; e += NTH) {
      const int t = e / (BTILE * INPUT);
      const int rem = e - t * (BTILE * INPUT);
      const int r = rem / INPUT, c = rem - r * INPUT;
      const float v = x[(size_t)t * xstep + (size_t)(brow0 + r) * INPUT + c];
      if (c < 32) lds[XOFF + t * X_T + r * X_ROW + c] = f2bf(v);
      else *(float*)(lds + XOFF + t * X_T + r * X_ROW + 36) = v;
    }
  }

  // store bases: out[b = brow0 + bt*16 + colA][j = c0 + jt*16 + kq*4 + i]
  float* o0 = out + (size_t)(brow0 + colA) * HID + c0 + kq * 4;
  float* o1 = o0 + (size_t)16 * HID;
  const int outstep = BATCH * HID;

  __syncthreads();   // x staged; h0 zeroed

  #pragma unroll 1
  for (int t2 = 0; t2 < T_SEQ / 2; ++t2) {
    CSTEP(H0, H1, 2 * t2);        // even: read buf0, write buf1
    CSTEP(H1, H0, 2 * t2 + 1);    // odd:  read buf1, write buf0
  }

  // h_last = h after step T-1 (bf16 restage readback from H0)
  {
    float* hp = out + (size_t)T_SEQ * BATCH * HID +
                (size_t)(brow0 + colA) * HID + c0 + kq * 4;
    #pragma unroll
    for (int jt = 0; jt < 2; ++jt)
      #pragma unroll
      for (int bt = 0; bt < 2; ++bt) {
        int2v dd = *(const int2v*)(lds + H0 + (bt * 16 + colA) * H_STRIDE +
                                   c0 + jt * 16 + kq * 4);
        float4v hv;
        hv[0] = __builtin_bit_cast(float, (unsigned)dd[0] << 16);
        hv[1] = __builtin_bit_cast(float, (unsigned)dd[0] & 0xFFFF0000u);
        hv[2] = __builtin_bit_cast(float, (unsigned)dd[1] << 16);
        hv[3] = __builtin_bit_cast(float, (unsigned)dd[1] & 0xFFFF0000u);
        *(float4v*)(hp + (size_t)(bt * 16) * HID + jt * 16) = hv;
      }
  }
}

extern "C" void kernel_launch(void* const* d_in, const int* in_sizes, int n_in,
                              void* d_out, int out_size, void* d_ws, size_t ws_size,
                              hipStream_t stream) {
  const float* x    = (const float*)d_in[0];
  const int*   sid  = (const int*)  d_in[1];
  const float* gts  = (const float*)d_in[2];
  const float* W_in = (const float*)d_in[3];
  const float* b_in = (const float*)d_in[4];
  const float* W_h  = (const float*)d_in[5];
  const float* b_h  = (const float*)d_in[6];
  float* out = (float*)d_out;

  (void)hipFuncSetAttribute(reinterpret_cast<const void*>(ctrnn_kernel),
                            hipFuncAttributeMaxDynamicSharedMemorySize,
                            (int)LDS_BYTES);
  ctrnn_kernel<<<BATCH / BTILE, NTH, LDS_BYTES, stream>>>(x, sid, gts, W_in,
                                                          b_in, W_h, b_h, out);
}

// Round 13
// 107.322 us; speedup vs baseline: 1.3745x; 1.3745x over previous
//
#include <hip/hip_runtime.h>

#define T_SEQ 50
#define BATCH 8192
#define INPUT 33
#define HID   256
#define BTILE 32
#define NTH   512

typedef __attribute__((ext_vector_type(8))) short short8;
typedef __attribute__((ext_vector_type(4))) float float4v;

// bf16 h / x staging, double-buffered (units: shorts)
#define H_STRIDE 264                       // 256 + 8 pad (2-way aliasing = free)
#define X_STRIDE 72                        // 64 + 8
#define H0 0
#define H1 (BTILE * H_STRIDE)              // 8448
#define X0 (2 * BTILE * H_STRIDE)          // 16896
#define X1 (X0 + BTILE * X_STRIDE)         // 19200
#define LDS_SHORTS (X1 + BTILE * X_STRIDE) // 21504 shorts = 43008 B

// f32 out-stage, double-buffered (units: floats), stride 260 (see R5 notes)
#define OUT_STRIDE 260
#define OUTBUF (BTILE * OUT_STRIDE)        // 8320 floats
// total LDS = 43008 + 2*8320*4 = 109568 B  (1 block/CU)

__device__ __forceinline__ short f2bf(float v) {   // RNE f32 -> bf16 bits
  unsigned u = __builtin_bit_cast(unsigned, v);
  u = (u + 0x7FFFu + ((u >> 16) & 1u)) >> 16;
  return (short)u;
}

// One step (R5 structure). ONLY change vs the 119.2-us baseline: the global
// output stores are NONTEMPORAL (nt) -> bypass L2 dirty-line allocation for
// the 437MB pure-streaming write. Everything else identical.
#define CSTEP(HR, XR, HW, XW, OW, T)                                          \
  {                                                                           \
    float xp0 = 0.f, xp1 = 0.f, xp2 = 0.f;                                    \
    const bool more = (T) + 1 < T_SEQ;                                        \
    if (more) {                                                               \
      const float* xt1 = xpf + (size_t)((T) + 1) * xstep;                     \
      xp0 = xt1[e0]; xp1 = xt1[e1];                                           \
      if (p2) xp2 = xt1[e2];                                                  \
    }                                                                         \
    float4v acc[2][2];                                                        \
    _Pragma("unroll") for (int m = 0; m < 2; ++m)                             \
      _Pragma("unroll") for (int n = 0; n < 2; ++n)                           \
        _Pragma("unroll") for (int i = 0; i < 4; ++i)                         \
          acc[m][n][i] = hst[m][n][i] + bc[n];                                \
    const short* hb = lds + (HR);                                             \
    const short* xb = lds + (XR);                                             \
    _Pragma("unroll") for (int ks = 0; ks < 8; ++ks) {                        \
      const int k = ks * 32 + kq * 8;                                         \
      short8 a0 = *(const short8*)(hb + colA * H_STRIDE + k);                 \
      short8 a1 = *(const short8*)(hb + (16 + colA) * H_STRIDE + k);          \
      acc[0][0] = __builtin_amdgcn_mfma_f32_16x16x32_bf16(a0, wf[0][ks], acc[0][0], 0, 0, 0); \
      acc[0][1] = __builtin_amdgcn_mfma_f32_16x16x32_bf16(a0, wf[1][ks], acc[0][1], 0, 0, 0); \
      acc[1][0] = __builtin_amdgcn_mfma_f32_16x16x32_bf16(a1, wf[0][ks], acc[1][0], 0, 0, 0); \
      acc[1][1] = __builtin_amdgcn_mfma_f32_16x16x32_bf16(a1, wf[1][ks], acc[1][1], 0, 0, 0); \
    }                                                                         \
    _Pragma("unroll") for (int kb = 0; kb < 2; ++kb) {                        \
      const int k = kb * 32 + kq * 8;                                         \
      short8 a0 = *(const short8*)(xb + colA * X_STRIDE + k);                 \
      short8 a1 = *(const short8*)(xb + (16 + colA) * X_STRIDE + k);          \
      acc[0][0] = __builtin_amdgcn_mfma_f32_16x16x32_bf16(a0, win[0][kb], acc[0][0], 0, 0, 0); \
      acc[0][1] = __builtin_amdgcn_mfma_f32_16x16x32_bf16(a0, win[1][kb], acc[0][1], 0, 0, 0); \
      acc[1][0] = __builtin_amdgcn_mfma_f32_16x16x32_bf16(a1, win[0][kb], acc[1][0], 0, 0, 0); \
      acc[1][1] = __builtin_amdgcn_mfma_f32_16x16x32_bf16(a1, win[1][kb], acc[1][1], 0, 0, 0); \
    }                                                                         \
    float* osw = outs + (OW) * OUTBUF;                                        \
    _Pragma("unroll") for (int m = 0; m < 2; ++m)                             \
      _Pragma("unroll") for (int n = 0; n < 2; ++n)                           \
        _Pragma("unroll") for (int i = 0; i < 4; ++i) {                       \
          float hn = fmaxf(0.5f * acc[m][n][i], 0.0f);                        \
          hst[m][n][i] = hn;                                                  \
          const int row = m * 16 + kq * 4 + i;                                \
          osw[row * OUT_STRIDE + c0 + n * 16 + colA] = hn;                    \
          lds[(HW) + row * H_STRIDE + c0 + n * 16 + colA] = f2bf(hn);         \
        }                                                                     \
    if (more) {                                                               \
      lds[(XW) + r0 * X_STRIDE + c0x] = f2bf(xp0);                            \
      lds[(XW) + r1 * X_STRIDE + c1x] = f2bf(xp1);                            \
      if (p2) lds[(XW) + r2 * X_STRIDE + c2x] = f2bf(xp2);                    \
    }                                                                         \
    __builtin_amdgcn_sched_barrier(0);                                        \
    asm volatile("s_waitcnt lgkmcnt(0)" ::: "memory");                        \
    __builtin_amdgcn_s_barrier();                                             \
    __builtin_amdgcn_sched_barrier(0);                                        \
    _Pragma("unroll") for (int j = 0; j < 4; ++j) {                           \
      float4v v = *(const float4v*)(osw + (4 * wave + j) * OUT_STRIDE + 4 * lane); \
      __builtin_nontemporal_store(v, (float4v*)(outg + j * HID));             \
    }                                                                         \
    outg += outstep;                                                          \
  }

__global__ __launch_bounds__(NTH, 2)
void ctrnn_kernel(const float* __restrict__ x, const int* __restrict__ sub_id,
                  const float* __restrict__ gates, const float* __restrict__ W_in,
                  const float* __restrict__ b_in, const float* __restrict__ W_h,
                  const float* __restrict__ b_h, float* __restrict__ out)
{
  __shared__ short lds[LDS_SHORTS];
  __shared__ float outs[2 * OUTBUF];
  const int tid  = threadIdx.x;
  const int lane = tid & 63;
  const int wave = tid >> 6;
  const int colA = lane & 15;   // MFMA row/col-within-tile index
  const int kq   = lane >> 4;   // k-quadrant / C-row group
  const int c0   = wave * 32;   // wave's output-column base (8 waves x 32)
  const int brow0 = blockIdx.x * BTILE;

  const int sid = sub_id[0];
  const float* grow = gates + sid * HID;

  // ---- zero h/x staging (h0 = 0; x pad columns stay 0 forever) ----
  {
    int* ldsi = (int*)lds;
    #pragma unroll 4
    for (int i = tid; i < LDS_SHORTS / 2; i += NTH) ldsi[i] = 0;
  }

  // ---- t-invariant operands in REGISTERS ----
  short8 wf[2][8];   // B-fragments of W_h' = diag(g)*W_h  (64 VGPRs)
  short8 win[2][2];  // B-fragments of W_in (zero-padded K=64)
  float  bc[2];
  #pragma unroll
  for (int n = 0; n < 2; ++n) {
    const int col = c0 + n * 16 + colA;
    const float g = grow[col];
    #pragma unroll
    for (int ks = 0; ks < 8; ++ks) {
      const float* wp = W_h + col * HID + ks * 32 + kq * 8;
      float4v w0 = *(const float4v*)wp;
      float4v w1 = *(const float4v*)(wp + 4);
      short8 f;
      f[0] = f2bf(g * w0[0]); f[1] = f2bf(g * w0[1]);
      f[2] = f2bf(g * w0[2]); f[3] = f2bf(g * w0[3]);
      f[4] = f2bf(g * w1[0]); f[5] = f2bf(g * w1[1]);
      f[6] = f2bf(g * w1[2]); f[7] = f2bf(g * w1[3]);
      wf[n][ks] = f;
    }
    #pragma unroll
    for (int kb = 0; kb < 2; ++kb) {
      short8 f;
      #pragma unroll
      for (int j = 0; j < 8; ++j) {
        int kk = kb * 32 + kq * 8 + j;
        f[j] = (kk < INPUT) ? f2bf(W_in[col * INPUT + kk]) : (short)0;
      }
      win[n][kb] = f;
    }
    bc[n] = b_in[col] + g * b_h[col];
  }

  __syncthreads();   // zero-fill complete before x0 staging

  // ---- stage x_0 into buffer 0 ----
  {
    const float* xt = x + (size_t)brow0 * INPUT;
    for (int e = tid; e < BTILE * INPUT; e += NTH) {
      int r = e / INPUT, c = e - r * INPUT;
      lds[X0 + r * X_STRIDE + c] = f2bf(xt[e]);
    }
  }

  // x-prefetch invariants (threads cover elems tid, tid+512, tid+1024 of 1056)
  const int e0 = tid, e1 = tid + NTH, e2 = tid + 2 * NTH;
  const int r0 = e0 / INPUT, c0x = e0 - r0 * INPUT;
  const int r1 = e1 / INPUT, c1x = e1 - r1 * INPUT;
  const int r2 = e2 / INPUT, c2x = e2 - r2 * INPUT;
  const bool p2 = (e2 < BTILE * INPUT);

  // persistent f32 h master at MFMA C-layout
  float4v hst[2][2];
  #pragma unroll
  for (int m = 0; m < 2; ++m)
    #pragma unroll
    for (int n = 0; n < 2; ++n)
      #pragma unroll
      for (int i = 0; i < 4; ++i) hst[m][n][i] = 0.0f;

  // coalesced store base: wave w owns tile rows 4w..4w+3, lane covers 16B
  float* outg = out + (size_t)(brow0 + 4 * wave) * HID + 4 * lane;
  const int outstep = BATCH * HID;
  const float* xpf = x + (size_t)brow0 * INPUT;
  const int xstep = BATCH * INPUT;

  __syncthreads();   // x0 staged; h0 zeroed

  #pragma unroll 1
  for (int t2 = 0; t2 < T_SEQ / 2; ++t2) {
    CSTEP(H0, X0, H1, X1, 0, 2 * t2);       // even: read buf0, write buf1
    CSTEP(H1, X1, H0, X0, 1, 2 * t2 + 1);   // odd:  read buf1, write buf0
  }

  // h_last == output[T-1]; its f32 rows are still staged in outs[1]
  {
    float* hl = out + (size_t)T_SEQ * BATCH * HID +
                (size_t)(brow0 + 4 * wave) * HID + 4 * lane;
    const float* osr = outs + OUTBUF;   // OW=1 held step T-1
    #pragma unroll
    for (int j = 0; j < 4; ++j) {
      float4v v = *(const float4v*)(osr + (4 * wave + j) * OUT_STRIDE + 4 * lane);
      __builtin_nontemporal_store(v, (float4v*)(hl + j * HID));
    }
  }
}

extern "C" void kernel_launch(void* const* d_in, const int* in_sizes, int n_in,
                              void* d_out, int out_size, void* d_ws, size_t ws_size,
                              hipStream_t stream) {
  const float* x    = (const float*)d_in[0];
  const int*   sid  = (const int*)  d_in[1];
  const float* gts  = (const float*)d_in[2];
  const float* W_in = (const float*)d_in[3];
  const float* b_in = (const float*)d_in[4];
  const float* W_h  = (const float*)d_in[5];
  const float* b_h  = (const float*)d_in[6];
  float* out = (float*)d_out;

  ctrnn_kernel<<<BATCH / BTILE, NTH, 0, stream>>>(x, sid, gts, W_in, b_in, W_h, b_h, out);
}

// Round 14
// 95.062 us; speedup vs baseline: 1.5518x; 1.1290x over previous
//
#include <hip/hip_runtime.h>

#define T_SEQ 50
#define BATCH 8192
#define INPUT 33
#define HID   256
#define BTILE 32
#define NTH   512

typedef __attribute__((ext_vector_type(8))) short short8;
typedef __attribute__((ext_vector_type(4))) short short4v;
typedef __attribute__((ext_vector_type(4))) float float4v;

// bf16 h / x staging, double-buffered (units: shorts). 43 KB total.
#define H_STRIDE 264                       // 256 + 8 pad (2-way aliasing = free)
#define X_STRIDE 72                        // 64 + 8
#define H0 0
#define H1 (BTILE * H_STRIDE)              // 8448
#define X0 (2 * BTILE * H_STRIDE)          // 16896
#define X1 (X0 + BTILE * X_STRIDE)         // 19200
#define LDS_SHORTS (X1 + BTILE * X_STRIDE) // 21504 shorts = 43008 B

__device__ __forceinline__ short f2bf(float v) {   // RNE f32 -> bf16 bits
  unsigned u = __builtin_bit_cast(unsigned, v);
  u = (u + 0x7FFFu + ((u >> 16) & 1u)) >> 16;
  return (short)u;
}
__device__ __forceinline__ float bf2f(short s) {
  return __builtin_bit_cast(float, ((unsigned)(unsigned short)s) << 16);
}

// One step (R13 structure minus the f32 out-stage). Output is read back from
// the just-written bf16 h buffer post-barrier (outputs pass through bf16 in
// the recurrence anyway; R7 validated absmax 0.03125), expanded to f32, and
// NONTEMPORAL-stored as contiguous 1KB rows. Saves 48KB/step/CU LDS traffic.
#define CSTEP(HR, XR, HW, XW, T)                                              \
  {                                                                           \
    float xp0 = 0.f, xp1 = 0.f, xp2 = 0.f;                                    \
    const bool more = (T) + 1 < T_SEQ;                                        \
    if (more) {                                                               \
      const float* xt1 = xpf + (size_t)((T) + 1) * xstep;                     \
      xp0 = xt1[e0]; xp1 = xt1[e1];                                           \
      if (p2) xp2 = xt1[e2];                                                  \
    }                                                                         \
    float4v acc[2][2];                                                        \
    _Pragma("unroll") for (int m = 0; m < 2; ++m)                             \
      _Pragma("unroll") for (int n = 0; n < 2; ++n)                           \
        _Pragma("unroll") for (int i = 0; i < 4; ++i)                         \
          acc[m][n][i] = hst[m][n][i] + bc[n];                                \
    const short* hb = lds + (HR);                                             \
    const short* xb = lds + (XR);                                             \
    _Pragma("unroll") for (int ks = 0; ks < 8; ++ks) {                        \
      const int k = ks * 32 + kq * 8;                                         \
      short8 a0 = *(const short8*)(hb + colA * H_STRIDE + k);                 \
      short8 a1 = *(const short8*)(hb + (16 + colA) * H_STRIDE + k);          \
      acc[0][0] = __builtin_amdgcn_mfma_f32_16x16x32_bf16(a0, wf[0][ks], acc[0][0], 0, 0, 0); \
      acc[0][1] = __builtin_amdgcn_mfma_f32_16x16x32_bf16(a0, wf[1][ks], acc[0][1], 0, 0, 0); \
      acc[1][0] = __builtin_amdgcn_mfma_f32_16x16x32_bf16(a1, wf[0][ks], acc[1][0], 0, 0, 0); \
      acc[1][1] = __builtin_amdgcn_mfma_f32_16x16x32_bf16(a1, wf[1][ks], acc[1][1], 0, 0, 0); \
    }                                                                         \
    _Pragma("unroll") for (int kb = 0; kb < 2; ++kb) {                        \
      const int k = kb * 32 + kq * 8;                                         \
      short8 a0 = *(const short8*)(xb + colA * X_STRIDE + k);                 \
      short8 a1 = *(const short8*)(xb + (16 + colA) * X_STRIDE + k);          \
      acc[0][0] = __builtin_amdgcn_mfma_f32_16x16x32_bf16(a0, win[0][kb], acc[0][0], 0, 0, 0); \
      acc[0][1] = __builtin_amdgcn_mfma_f32_16x16x32_bf16(a0, win[1][kb], acc[0][1], 0, 0, 0); \
      acc[1][0] = __builtin_amdgcn_mfma_f32_16x16x32_bf16(a1, win[0][kb], acc[1][0], 0, 0, 0); \
      acc[1][1] = __builtin_amdgcn_mfma_f32_16x16x32_bf16(a1, win[1][kb], acc[1][1], 0, 0, 0); \
    }                                                                         \
    _Pragma("unroll") for (int m = 0; m < 2; ++m)                             \
      _Pragma("unroll") for (int n = 0; n < 2; ++n)                           \
        _Pragma("unroll") for (int i = 0; i < 4; ++i) {                       \
          float hn = fmaxf(0.5f * acc[m][n][i], 0.0f);                        \
          hst[m][n][i] = hn;                                                  \
          lds[(HW) + (m * 16 + kq * 4 + i) * H_STRIDE + c0 + n * 16 + colA] = \
              f2bf(hn);                                                       \
        }                                                                     \
    if (more) {                                                               \
      lds[(XW) + r0 * X_STRIDE + c0x] = f2bf(xp0);                            \
      lds[(XW) + r1 * X_STRIDE + c1x] = f2bf(xp1);                            \
      if (p2) lds[(XW) + r2 * X_STRIDE + c2x] = f2bf(xp2);                    \
    }                                                                         \
    __builtin_amdgcn_sched_barrier(0);                                        \
    asm volatile("s_waitcnt lgkmcnt(0)" ::: "memory");                        \
    __builtin_amdgcn_s_barrier();                                             \
    __builtin_amdgcn_sched_barrier(0);                                        \
    _Pragma("unroll") for (int j = 0; j < 4; ++j) {                           \
      short4v hv = *(const short4v*)(lds + (HW) + (4 * wave + j) * H_STRIDE + 4 * lane); \
      float4v ov;                                                             \
      ov[0] = bf2f(hv[0]); ov[1] = bf2f(hv[1]);                               \
      ov[2] = bf2f(hv[2]); ov[3] = bf2f(hv[3]);                               \
      __builtin_nontemporal_store(ov, (float4v*)(outg + j * HID));            \
    }                                                                         \
    outg += outstep;                                                          \
  }

__global__ __launch_bounds__(NTH, 2)
void ctrnn_kernel(const float* __restrict__ x, const int* __restrict__ sub_id,
                  const float* __restrict__ gates, const float* __restrict__ W_in,
                  const float* __restrict__ b_in, const float* __restrict__ W_h,
                  const float* __restrict__ b_h, float* __restrict__ out)
{
  __shared__ short lds[LDS_SHORTS];
  const int tid  = threadIdx.x;
  const int lane = tid & 63;
  const int wave = tid >> 6;
  const int colA = lane & 15;   // MFMA row/col-within-tile index
  const int kq   = lane >> 4;   // k-quadrant / C-row group
  const int c0   = wave * 32;   // wave's output-column base (8 waves x 32)
  const int brow0 = blockIdx.x * BTILE;

  const int sid = sub_id[0];
  const float* grow = gates + sid * HID;

  // ---- zero h/x staging (h0 = 0; x pad columns stay 0 forever) ----
  {
    int* ldsi = (int*)lds;
    #pragma unroll 4
    for (int i = tid; i < LDS_SHORTS / 2; i += NTH) ldsi[i] = 0;
  }

  // ---- t-invariant operands in REGISTERS ----
  short8 wf[2][8];   // B-fragments of W_h' = diag(g)*W_h  (64 VGPRs)
  short8 win[2][2];  // B-fragments of W_in (zero-padded K=64)
  float  bc[2];
  #pragma unroll
  for (int n = 0; n < 2; ++n) {
    const int col = c0 + n * 16 + colA;
    const float g = grow[col];
    #pragma unroll
    for (int ks = 0; ks < 8; ++ks) {
      const float* wp = W_h + col * HID + ks * 32 + kq * 8;
      float4v w0 = *(const float4v*)wp;
      float4v w1 = *(const float4v*)(wp + 4);
      short8 f;
      f[0] = f2bf(g * w0[0]); f[1] = f2bf(g * w0[1]);
      f[2] = f2bf(g * w0[2]); f[3] = f2bf(g * w0[3]);
      f[4] = f2bf(g * w1[0]); f[5] = f2bf(g * w1[1]);
      f[6] = f2bf(g * w1[2]); f[7] = f2bf(g * w1[3]);
      wf[n][ks] = f;
    }
    #pragma unroll
    for (int kb = 0; kb < 2; ++kb) {
      short8 f;
      #pragma unroll
      for (int j = 0; j < 8; ++j) {
        int kk = kb * 32 + kq * 8 + j;
        f[j] = (kk < INPUT) ? f2bf(W_in[col * INPUT + kk]) : (short)0;
      }
      win[n][kb] = f;
    }
    bc[n] = b_in[col] + g * b_h[col];
  }

  __syncthreads();   // zero-fill complete before x0 staging

  // ---- stage x_0 into buffer 0 ----
  {
    const float* xt = x + (size_t)brow0 * INPUT;
    for (int e = tid; e < BTILE * INPUT; e += NTH) {
      int r = e / INPUT, c = e - r * INPUT;
      lds[X0 + r * X_STRIDE + c] = f2bf(xt[e]);
    }
  }

  // x-prefetch invariants (threads cover elems tid, tid+512, tid+1024 of 1056)
  const int e0 = tid, e1 = tid + NTH, e2 = tid + 2 * NTH;
  const int r0 = e0 / INPUT, c0x = e0 - r0 * INPUT;
  const int r1 = e1 / INPUT, c1x = e1 - r1 * INPUT;
  const int r2 = e2 / INPUT, c2x = e2 - r2 * INPUT;
  const bool p2 = (e2 < BTILE * INPUT);

  // persistent f32 h master at MFMA C-layout
  float4v hst[2][2];
  #pragma unroll
  for (int m = 0; m < 2; ++m)
    #pragma unroll
    for (int n = 0; n < 2; ++n)
      #pragma unroll
      for (int i = 0; i < 4; ++i) hst[m][n][i] = 0.0f;

  // coalesced store base: wave w owns tile rows 4w..4w+3, lane covers 16B
  float* outg = out + (size_t)(brow0 + 4 * wave) * HID + 4 * lane;
  const int outstep = BATCH * HID;
  const float* xpf = x + (size_t)brow0 * INPUT;
  const int xstep = BATCH * INPUT;

  __syncthreads();   // x0 staged; h0 zeroed

  #pragma unroll 1
  for (int t2 = 0; t2 < T_SEQ / 2; ++t2) {
    CSTEP(H0, X0, H1, X1, 2 * t2);       // even: read buf0, write buf1
    CSTEP(H1, X1, H0, X0, 2 * t2 + 1);   // odd:  read buf1, write buf0
  }

  // h_last == output[T-1]; read back from H0 (written by step T-1)
  {
    float* hl = out + (size_t)T_SEQ * BATCH * HID +
                (size_t)(brow0 + 4 * wave) * HID + 4 * lane;
    #pragma unroll
    for (int j = 0; j < 4; ++j) {
      short4v hv = *(const short4v*)(lds + H0 + (4 * wave + j) * H_STRIDE + 4 * lane);
      float4v ov;
      ov[0] = bf2f(hv[0]); ov[1] = bf2f(hv[1]);
      ov[2] = bf2f(hv[2]); ov[3] = bf2f(hv[3]);
      __builtin_nontemporal_store(ov, (float4v*)(hl + j * HID));
    }
  }
}

extern "C" void kernel_launch(void* const* d_in, const int* in_sizes, int n_in,
                              void* d_out, int out_size, void* d_ws, size_t ws_size,
                              hipStream_t stream) {
  const float* x    = (const float*)d_in[0];
  const int*   sid  = (const int*)  d_in[1];
  const float* gts  = (const float*)d_in[2];
  const float* W_in = (const float*)d_in[3];
  const float* b_in = (const float*)d_in[4];
  const float* W_h  = (const float*)d_in[5];
  const float* b_h  = (const float*)d_in[6];
  float* out = (float*)d_out;

  ctrnn_kernel<<<BATCH / BTILE, NTH, 0, stream>>>(x, sid, gts, W_in, b_in, W_h, b_h, out);
}